// Round 6
// baseline (191.003 us; speedup 1.0000x reference)
//
#include <hip/hip_runtime.h>
#include <math.h>

#define HH 512
#define WW 512
#define BB 4
#define NCLS 20
#define NINST 32
#define NPIX (HH*WW)
#define NCH 24
#define KB2 256
#define INV_BIN 128.0f           // err * 128 -> bin;  bin width = 1/128
#define NCHUNK 128
#define CHUNKPIX (NPIX/NCHUNK)   // 2048
#define K3T 256
#define JH 16                    // instances per K3 block (half)

// ---- workspace layout (bytes) ----
#define OFF_STATS  ((size_t)0)                       // 8 fields x 128 floats
#define OFF_CLS    (OFF_STATS + 8*128*4)
#define OFF_SEED   (OFF_CLS + 128*4)                 // seedbg[4], seedfg[4]
#define ZERO_BYTES (OFF_SEED + 8*4)
#define OFF_DER    (ZERO_BYTES)                      // 7 x 128 floats
#define OFF_INSTL  (OFF_DER + 7*128*4)
#define OFF_HIST   (OFF_INSTL + 128*4)               // u32[B][NCHUNK][NINST][KB2] = 16 MB

__device__ __forceinline__ float fast_exp(float x) { return __expf(x); }
__device__ __forceinline__ float fast_rcp(float x) { return __builtin_amdgcn_rcpf(x); }
__device__ __forceinline__ float fast_sigmoid(float z) { return fast_rcp(1.0f + __expf(-z)); }
__device__ __forceinline__ float fast_tanh(float x) {
  return 1.0f - 2.0f * fast_rcp(__expf(2.0f * x) + 1.0f);
}

// K1: per-pixel stats. 4 consecutive pixels/thread, float4/int4 loads.
// Per-wave LDS stat copies (stride 9); cnt and G packed into one int atomic.
__global__ __launch_bounds__(256) void k1_stats(
    const float* __restrict__ pred, const int* __restrict__ inst,
    const int* __restrict__ lab,
    float* __restrict__ stats, int* __restrict__ clsg, float* __restrict__ seedbg)
{
  __shared__ unsigned s_st[4][NINST][9];  // [0]=cnt|G<<16 (int), [1..6]=float bits
  __shared__ int s_cls[NINST];
  __shared__ float s_seed;
  int t = threadIdx.x;
  int w = t >> 6;
  for (int i = t; i < 4*NINST*9; i += 256) ((unsigned*)s_st)[i] = 0u;
  if (t < NINST) s_cls[t] = 0;
  if (t == 0) s_seed = 0.f;
  __syncthreads();

  int b = blockIdx.x >> 8;
  int p = (blockIdx.x & 255) * 1024 + t * 4;   // 4 consecutive pixels
  const float* pb = pred + (size_t)b*NCH*NPIX;
  float4 g0v = *(const float4*)(pb + 2*NPIX + p);
  float4 g1v = *(const float4*)(pb + 3*NPIX + p);
  int4 idv = *(const int4*)(inst + (size_t)b*NPIX + p);
  int4 lbv = *(const int4*)(lab + (size_t)b*NPIX + p);

  #pragma unroll
  for (int u = 0; u < 4; ++u) {
    int px = p + u;
    int x = px & (WW-1);
    int y = px >> 9;
    float xm = x * (1.0f/(WW-1));
    float ym = y * (1.0f/(HH-1));
    float g0 = (&g0v.x)[u];
    float g1 = (&g1v.x)[u];
    int id = (&idv.x)[u];
    int lb = (&lbv.x)[u];
    if (id >= 1) {
      int j = id - 1;
      unsigned* row = s_st[w][j];
      atomicAdd(&row[0], 1u | ((lb != 255) ? 0x10000u : 0u));
      atomicAdd((float*)&row[1], xm);
      atomicAdd((float*)&row[2], ym);
      atomicAdd((float*)&row[3], g0);
      atomicAdd((float*)&row[4], g1);
      atomicAdd((float*)&row[5], g0*g0);
      atomicAdd((float*)&row[6], g1*g1);
      atomicMax(&s_cls[j], lb);
    }
  }

  float seedloc = 0.f;
  for (int c = 0; c < NCLS; ++c) {
    float4 sv = *(const float4*)(pb + (size_t)(4+c)*NPIX + p);
    #pragma unroll
    for (int u = 0; u < 4; ++u) {
      int lb = (&lbv.x)[u];
      if (lb != 255 && (c + 1 != lb)) {
        float sg = fast_sigmoid((&sv.x)[u]);
        seedloc += sg*sg;
      }
    }
  }
  for (int o = 32; o; o >>= 1) seedloc += __shfl_down(seedloc, o);
  if ((t & 63) == 0) atomicAdd(&s_seed, seedloc);
  __syncthreads();
  {
    int j = t >> 3, f = t & 7;
    float v;
    if (f == 0) {
      unsigned s = (s_st[0][j][0] & 0xFFFFu) + (s_st[1][j][0] & 0xFFFFu)
                 + (s_st[2][j][0] & 0xFFFFu) + (s_st[3][j][0] & 0xFFFFu);
      v = (float)s;
    } else if (f == 7) {
      unsigned s = (s_st[0][j][0] >> 16) + (s_st[1][j][0] >> 16)
                 + (s_st[2][j][0] >> 16) + (s_st[3][j][0] >> 16);
      v = (float)s;
    } else {
      v = __uint_as_float(s_st[0][j][f]) + __uint_as_float(s_st[1][j][f])
        + __uint_as_float(s_st[2][j][f]) + __uint_as_float(s_st[3][j][f]);
    }
    if (v != 0.f) atomicAdd(&stats[f*128 + b*NINST + j], v);
  }
  if (t < NINST) atomicMax(&clsg[b*NINST + t], s_cls[t]);
  if (t == 0) atomicAdd(&seedbg[b], s_seed);
}

// K2: derive per-pair quantities.
__global__ void k2_derive(const float* __restrict__ stats, const int* __restrict__ clsg,
                          float* __restrict__ der)
{
  int pair = threadIdx.x;
  float cntA = stats[0*128+pair];
  float cnt = fmaxf(cntA, 1.0f);
  float sumx = stats[1*128+pair], sumy = stats[2*128+pair];
  float s0 = stats[3*128+pair], s1 = stats[4*128+pair];
  float q0 = stats[5*128+pair], q1 = stats[6*128+pair];
  float Gv = stats[7*128+pair];
  float cx = sumx/cnt, cy = sumy/cnt;
  float sm0 = s0/cnt, sm1 = s1/cnt;
  float varnum = q0 - 2.f*sm0*s0 + cntA*sm0*sm0
               + q1 - 2.f*sm1*s1 + cntA*sm1*sm1;
  float varl = varnum / (2.0f * cnt);
  int cls = clsg[pair] - 1; if (cls < 0) cls = 0;
  der[0*128+pair] = cx;
  der[1*128+pair] = cy;
  der[2*128+pair] = expf(10.f*sm0);
  der[3*128+pair] = expf(10.f*sm1);
  der[4*128+pair] = varl;
  der[5*128+pair] = Gv;
  der[6*128+pair] = (float)cls;
}

// K3: block = (image, chunk, half). 16 instance histograms in 16 KB LDS.
// Each thread owns 8 CONSECUTIVE pixels; per-instance (cur_bin, acc) run
// aggregation in registers -> ~4x fewer LDS atomics, diverse addresses.
__global__ __launch_bounds__(K3T) void k3_hist(
    const float* __restrict__ pred, const int* __restrict__ inst,
    const int* __restrict__ lab, const float* __restrict__ der,
    unsigned* __restrict__ hist, float* __restrict__ seedfg)
{
  __shared__ unsigned hc[JH*KB2];         // 16 KB
  int t = threadIdx.x;
  int bid = blockIdx.x;                   // B*NCHUNK*2 = 1024
  int half = bid & 1;
  int chunk = (bid >> 1) & (NCHUNK-1);
  int b = bid >> 8;
  {
    uint4* hv = (uint4*)hc;
    uint4 z = make_uint4(0,0,0,0);
    #pragma unroll
    for (int i = 0; i < JH*KB2/4/K3T; ++i) hv[i*K3T + t] = z;
  }
  __syncthreads();

  const float* pb = pred + (size_t)b*NCH*NPIX;
  const int* ib = inst + (size_t)b*NPIX;
  const int* lb = lab + (size_t)b*NPIX;
  int base = chunk * CHUNKPIX + t * 8;    // 8 consecutive pixels

  unsigned curb[JH], acc[JH];
  #pragma unroll
  for (int jj = 0; jj < JH; ++jj) { curb[jj] = 0xFFFFFFFFu; acc[jj] = 0u; }
  float fg = 0.f;

  #pragma unroll
  for (int q = 0; q < 2; ++q) {
    int p = base + q*4;
    float4 r0 = *(const float4*)(pb + p);
    float4 r1 = *(const float4*)(pb + NPIX + p);
    int4 idv = *(const int4*)(ib + p);
    int4 lbv = *(const int4*)(lb + p);
    float ex[4], ey[4], sg[4];
    int idu[4]; bool vld[4];
    #pragma unroll
    for (int u = 0; u < 4; ++u) {
      int px = p + u;
      int x = px & (WW-1);
      int y = px >> 9;
      ex[u] = fast_tanh((&r0.x)[u]) + x * (1.0f/(WW-1));
      ey[u] = fast_tanh((&r1.x)[u]) + y * (1.0f/(HH-1));
      idu[u] = (&idv.x)[u];
      vld[u] = ((&lbv.x)[u] != 255);
      sg[u] = 0.f;
      if (idu[u] >= 1 && ((idu[u]-1) >> 4) == half) {
        int cls = (int)der[6*128 + b*NINST + idu[u]-1];
        sg[u] = fast_sigmoid(pb[(size_t)(4+cls)*NPIX + px]);
      }
    }
    #pragma unroll
    for (int jj = 0; jj < JH; ++jj) {
      int j = half*JH + jj;
      int pair = b*NINST + j;
      float cx = der[0*128+pair], cy = der[1*128+pair];
      float s0 = der[2*128+pair], s1 = der[3*128+pair];
      #pragma unroll
      for (int u = 0; u < 4; ++u) {
        float dx = ex[u] - cx, dy = ey[u] - cy;
        float dist = fast_exp(-(dx*dx*s0 + dy*dy*s1));
        bool own = (idu[u] == j+1);
        if (own) { float d = sg[u] - dist; fg += d*d; }
        if (vld[u]) {
          float f = own ? (1.0f - dist) : dist;      // err/2
          unsigned bin = min((unsigned)(f * (2.0f*INV_BIN)), KB2-1u);
          unsigned v = own ? 0x10001u : 1u;
          if (bin == curb[jj]) {
            acc[jj] += v;
          } else {
            if (curb[jj] != 0xFFFFFFFFu) atomicAdd(&hc[jj*KB2 + curb[jj]], acc[jj]);
            curb[jj] = bin; acc[jj] = v;
          }
        }
      }
    }
  }
  #pragma unroll
  for (int jj = 0; jj < JH; ++jj)
    if (curb[jj] != 0xFFFFFFFFu) atomicAdd(&hc[jj*KB2 + curb[jj]], acc[jj]);

  for (int o = 32; o; o >>= 1) fg += __shfl_down(fg, o);
  if ((t & 63) == 0) atomicAdd(&seedfg[b], 10.0f * fg);   // fg_w = 10

  __syncthreads();
  {
    uint4* dst = (uint4*)(hist + (((size_t)b*NCHUNK + chunk)*NINST + half*JH)*KB2);
    const uint4* src = (const uint4*)hc;
    #pragma unroll
    for (int i = 0; i < JH*KB2/4/K3T; ++i) dst[i*K3T + t] = src[i*K3T + t];
  }
}

// K4: per pair: 1024 threads; 4 groups each reduce 32 chunk-histograms,
// combine in LDS, then one wave does the descending Lovasz scan.
__global__ __launch_bounds__(1024) void k4_scan(
    const unsigned* __restrict__ hist, const float* __restrict__ der,
    float* __restrict__ instl)
{
  __shared__ unsigned s_c[4][KB2], s_p[4][KB2];
  int t = threadIdx.x;
  int pair = blockIdx.x;
  int b = pair >> 5, j = pair & 31;
  int bin = t & (KB2-1), grp = t >> 8;
  const unsigned* basep = hist + ((size_t)b*NCHUNK*NINST + j)*KB2 + bin;
  unsigned c = 0, p = 0;
  #pragma unroll 8
  for (int ch = grp*(NCHUNK/4); ch < (grp+1)*(NCHUNK/4); ++ch) {
    unsigned v = basep[(size_t)ch * (NINST*KB2)];
    c += v & 0xFFFFu; p += v >> 16;
  }
  s_c[grp][bin] = c; s_p[grp][bin] = p;
  __syncthreads();
  if (t < KB2) {
    s_c[0][t] = s_c[0][t] + s_c[1][t] + s_c[2][t] + s_c[3][t];
    s_p[0][t] = s_p[0][t] + s_p[1][t] + s_p[2][t] + s_p[3][t];
  }
  __syncthreads();

  if (t < 64) {
    int lane = t;
    float G = der[5*128+pair];
    unsigned carryN = 0, carryP = 0;
    float Jprev = 0.f, L = 0.f;
    for (int c8 = 0; c8 < KB2/64; ++c8) {
      int k = KB2 - 1 - c8*64 - lane;
      unsigned n = s_c[0][k], pp0 = s_p[0][k];
      for (int off = 1; off < 64; off <<= 1) {
        unsigned nn = __shfl_up(n, off);
        unsigned pp = __shfl_up(pp0, off);
        if (lane >= off) { n += nn; pp0 += pp; }
      }
      float fN = (float)(carryN + n);
      float fP = (float)(carryP + pp0);
      float uni = G + fN - fP;
      float J = 1.0f - (G - fP) / fmaxf(uni, 1e-9f);
      float Jp = __shfl_up(J, 1);
      if (lane == 0) Jp = Jprev;
      float v = (k + 0.5f) * (1.0f/INV_BIN);
      L += v * (J - Jp);
      carryN += __shfl(n, 63);
      carryP += __shfl(pp0, 63);
      Jprev  = __shfl(J, 63);
    }
    for (int o = 32; o; o >>= 1) L += __shfl_down(L, o);
    if (lane == 0) instl[pair] = L;
  }
}

// K5: final combine.
__global__ void k5_final(const float* __restrict__ instl, const float* __restrict__ der,
                         const float* __restrict__ seedbg, const float* __restrict__ seedfg,
                         float* __restrict__ out)
{
  __shared__ float red[128];
  int t = threadIdx.x;
  float v = instl[t]*(1.0f/NINST) + 10.0f*der[4*128+t]*(1.0f/NINST);
  red[t] = v; __syncthreads();
  for (int s = 64; s; s >>= 1) { if (t < s) red[t] += red[t+s]; __syncthreads(); }
  if (t == 0) {
    float tot = red[0];
    for (int b = 0; b < BB; ++b) tot += (seedbg[b] + seedfg[b]) * (1.0f/NPIX);
    out[0] = tot * (1.0f/BB);
  }
}

extern "C" void kernel_launch(void* const* d_in, const int* in_sizes, int n_in,
                              void* d_out, int out_size, void* d_ws, size_t ws_size,
                              hipStream_t stream)
{
  const float* pred = (const float*)d_in[0];
  const int* inst = (const int*)d_in[1];
  const int* lab  = (const int*)d_in[2];
  char* ws = (char*)d_ws;
  float* stats = (float*)(ws + OFF_STATS);
  int* clsg = (int*)(ws + OFF_CLS);
  float* seedbg = (float*)(ws + OFF_SEED);
  float* seedfg = seedbg + 4;
  float* der = (float*)(ws + OFF_DER);
  float* instl = (float*)(ws + OFF_INSTL);
  unsigned* hist = (unsigned*)(ws + OFF_HIST);

  hipMemsetAsync(ws, 0, ZERO_BYTES, stream);
  hipLaunchKernelGGL(k1_stats, dim3(BB*256), dim3(256), 0, stream,
                     pred, inst, lab, stats, clsg, seedbg);
  hipLaunchKernelGGL(k2_derive, dim3(1), dim3(128), 0, stream, stats, clsg, der);
  hipLaunchKernelGGL(k3_hist, dim3(BB*NCHUNK*2), dim3(K3T), 0, stream,
                     pred, inst, lab, der, hist, seedfg);
  hipLaunchKernelGGL(k4_scan, dim3(128), dim3(1024), 0, stream, hist, der, instl);
  hipLaunchKernelGGL(k5_final, dim3(1), dim3(128), 0, stream, instl, der, seedbg, seedfg, (float*)d_out);
}

// Round 7
// 144.757 us; speedup vs baseline: 1.3195x; 1.3195x over previous
//
#include <hip/hip_runtime.h>
#include <math.h>

#define HH 512
#define WW 512
#define BB 4
#define NCLS 20
#define NINST 32
#define NPIX (HH*WW)
#define NCH 24
#define KB2 256
#define INV_BIN 128.0f           // err * 128 -> bin;  bin width = 1/128
#define NCHUNK 128
#define CHUNKPIX (NPIX/NCHUNK)   // 2048
#define K3T 512

// ---- workspace layout (bytes) ----
#define OFF_STATS  ((size_t)0)                       // 8 fields x 128 floats
#define OFF_CLS    (OFF_STATS + 8*128*4)
#define OFF_SEED   (OFF_CLS + 128*4)                 // seedbg[4], seedfg[4]
#define ZERO_BYTES (OFF_SEED + 8*4)
#define OFF_DER    (ZERO_BYTES)                      // 7 x 128 floats
#define OFF_INSTL  (OFF_DER + 7*128*4)
#define OFF_SGOWN  ((OFF_INSTL + 128*4 + 255) & ~(size_t)255)  // u16[B][NPIX] = 2 MB
#define OFF_HIST   (OFF_SGOWN + (size_t)BB*NPIX*2)   // u32[B][NCHUNK][NINST][KB2] = 16 MB

__device__ __forceinline__ float fast_exp(float x) { return __expf(x); }
__device__ __forceinline__ float fast_rcp(float x) { return __builtin_amdgcn_rcpf(x); }
__device__ __forceinline__ float fast_sigmoid(float z) { return fast_rcp(1.0f + __expf(-z)); }
__device__ __forceinline__ float fast_tanh(float x) {
  return 1.0f - 2.0f * fast_rcp(__expf(2.0f * x) + 1.0f);
}

// K1: per-pixel stats, class, seed_bg, and per-pixel own-class sigmoid (u16).
__global__ __launch_bounds__(256) void k1_stats(
    const float* __restrict__ pred, const int* __restrict__ inst,
    const int* __restrict__ lab,
    float* __restrict__ stats, int* __restrict__ clsg, float* __restrict__ seedbg,
    unsigned short* __restrict__ sgown)
{
  __shared__ unsigned s_st[4][NINST][9];  // [0]=cnt|G<<16, [1..6]=float bits
  __shared__ int s_cls[NINST];
  __shared__ float s_seed;
  int t = threadIdx.x;
  int w = t >> 6;
  for (int i = t; i < 4*NINST*9; i += 256) ((unsigned*)s_st)[i] = 0u;
  if (t < NINST) s_cls[t] = 0;
  if (t == 0) s_seed = 0.f;
  __syncthreads();

  int b = blockIdx.x >> 8;
  int p = (blockIdx.x & 255) * 1024 + t * 4;   // 4 consecutive pixels
  const float* pb = pred + (size_t)b*NCH*NPIX;
  float4 g0v = *(const float4*)(pb + 2*NPIX + p);
  float4 g1v = *(const float4*)(pb + 3*NPIX + p);
  int4 idv = *(const int4*)(inst + (size_t)b*NPIX + p);
  int4 lbv = *(const int4*)(lab + (size_t)b*NPIX + p);

  #pragma unroll
  for (int u = 0; u < 4; ++u) {
    int px = p + u;
    int x = px & (WW-1);
    int y = px >> 9;
    float xm = x * (1.0f/(WW-1));
    float ym = y * (1.0f/(HH-1));
    float g0 = (&g0v.x)[u];
    float g1 = (&g1v.x)[u];
    int id = (&idv.x)[u];
    int lb = (&lbv.x)[u];
    if (id >= 1) {
      int j = id - 1;
      unsigned* row = s_st[w][j];
      atomicAdd(&row[0], 1u | ((lb != 255) ? 0x10000u : 0u));
      atomicAdd((float*)&row[1], xm);
      atomicAdd((float*)&row[2], ym);
      atomicAdd((float*)&row[3], g0);
      atomicAdd((float*)&row[4], g1);
      atomicAdd((float*)&row[5], g0*g0);
      atomicAdd((float*)&row[6], g1*g1);
      atomicMax(&s_cls[j], lb);
    }
  }

  float seedloc = 0.f;
  unsigned short so[4] = {0,0,0,0};
  for (int c = 0; c < NCLS; ++c) {
    float4 sv = *(const float4*)(pb + (size_t)(4+c)*NPIX + p);
    #pragma unroll
    for (int u = 0; u < 4; ++u) {
      int lb = (&lbv.x)[u];
      if (lb != 255) {
        float sg = fast_sigmoid((&sv.x)[u]);
        if (c + 1 == lb) so[u] = (unsigned short)(sg*65535.f + 0.5f);
        else seedloc += sg*sg;
      }
    }
  }
  {
    ushort4 sv4; sv4.x = so[0]; sv4.y = so[1]; sv4.z = so[2]; sv4.w = so[3];
    *(ushort4*)(sgown + (size_t)b*NPIX + p) = sv4;
  }
  for (int o = 32; o; o >>= 1) seedloc += __shfl_down(seedloc, o);
  if ((t & 63) == 0) atomicAdd(&s_seed, seedloc);
  __syncthreads();
  {
    int j = t >> 3, f = t & 7;
    float v;
    if (f == 0) {
      unsigned s = (s_st[0][j][0] & 0xFFFFu) + (s_st[1][j][0] & 0xFFFFu)
                 + (s_st[2][j][0] & 0xFFFFu) + (s_st[3][j][0] & 0xFFFFu);
      v = (float)s;
    } else if (f == 7) {
      unsigned s = (s_st[0][j][0] >> 16) + (s_st[1][j][0] >> 16)
                 + (s_st[2][j][0] >> 16) + (s_st[3][j][0] >> 16);
      v = (float)s;
    } else {
      v = __uint_as_float(s_st[0][j][f]) + __uint_as_float(s_st[1][j][f])
        + __uint_as_float(s_st[2][j][f]) + __uint_as_float(s_st[3][j][f]);
    }
    if (v != 0.f) atomicAdd(&stats[f*128 + b*NINST + j], v);
  }
  if (t < NINST) atomicMax(&clsg[b*NINST + t], s_cls[t]);
  if (t == 0) atomicAdd(&seedbg[b], s_seed);
}

// K2: derive per-pair quantities.
__global__ void k2_derive(const float* __restrict__ stats, const int* __restrict__ clsg,
                          float* __restrict__ der)
{
  int pair = threadIdx.x;
  float cntA = stats[0*128+pair];
  float cnt = fmaxf(cntA, 1.0f);
  float sumx = stats[1*128+pair], sumy = stats[2*128+pair];
  float s0 = stats[3*128+pair], s1 = stats[4*128+pair];
  float q0 = stats[5*128+pair], q1 = stats[6*128+pair];
  float Gv = stats[7*128+pair];
  float cx = sumx/cnt, cy = sumy/cnt;
  float sm0 = s0/cnt, sm1 = s1/cnt;
  float varnum = q0 - 2.f*sm0*s0 + cntA*sm0*sm0
               + q1 - 2.f*sm1*s1 + cntA*sm1*sm1;
  float varl = varnum / (2.0f * cnt);
  int cls = clsg[pair] - 1; if (cls < 0) cls = 0;
  der[0*128+pair] = cx;
  der[1*128+pair] = cy;
  der[2*128+pair] = expf(10.f*sm0);
  der[3*128+pair] = expf(10.f*sm1);
  der[4*128+pair] = varl;
  der[5*128+pair] = Gv;
  der[6*128+pair] = (float)cls;
}

// K3: block = (image, 2048-pixel chunk). Stage pixels to LDS once; compute
// with INSTANCE-PARALLEL lanes: lane = (pixel-slot<<5) | instance. One wave
// atomic hits 32 different histogram rows -> no same-address serialization.
__global__ __launch_bounds__(K3T) void k3_hist(
    const float* __restrict__ pred, const int* __restrict__ inst,
    const int* __restrict__ lab, const unsigned short* __restrict__ sgown,
    const float* __restrict__ der,
    unsigned* __restrict__ hist, float* __restrict__ seedfg)
{
  __shared__ float4 st[CHUNKPIX];         // {ex, ey, sg_own, meta} 32 KB
  __shared__ unsigned hc[NINST*KB2];      // 32 KB
  int t = threadIdx.x;
  int b = blockIdx.x >> 7;
  int chunk = blockIdx.x & (NCHUNK-1);
  {
    uint4* hv = (uint4*)hc;
    uint4 z = make_uint4(0,0,0,0);
    #pragma unroll
    for (int i = 0; i < NINST*KB2/4/K3T; ++i) hv[i*K3T + t] = z;
  }

  const float* pb = pred + (size_t)b*NCH*NPIX;
  int base = chunk * CHUNKPIX;
  {
    int p = base + t*4;
    float4 c0 = *(const float4*)(pb + p);
    float4 c1 = *(const float4*)(pb + NPIX + p);
    ushort4 sg4 = *(const ushort4*)(sgown + (size_t)b*NPIX + p);
    int4 idv = *(const int4*)(inst + (size_t)b*NPIX + p);
    int4 lbv = *(const int4*)(lab + (size_t)b*NPIX + p);
    #pragma unroll
    for (int u = 0; u < 4; ++u) {
      int px = p + u;
      int x = px & (WW-1);
      int y = px >> 9;
      float ex = fast_tanh((&c0.x)[u]) + x * (1.0f/(WW-1));
      float ey = fast_tanh((&c1.x)[u]) + y * (1.0f/(HH-1));
      float sg = (float)((&sg4.x)[u]) * (1.0f/65535.f);
      unsigned meta = (unsigned)(&idv.x)[u] | (((&lbv.x)[u] != 255) ? 0x100u : 0u);
      st[t*4 + u] = make_float4(ex, ey, sg, __uint_as_float(meta));
    }
  }
  __syncthreads();

  int lane = t & 63;
  int w = t >> 6;                         // 8 waves
  int j = lane & 31;                      // instance
  int pair = b*NINST + j;
  float cx = der[0*128+pair], cy = der[1*128+pair];
  float s0 = der[2*128+pair], s1 = der[3*128+pair];
  int pixbase = w*256 + (lane >> 5)*128;  // slot A: +0, slot B: +128
  unsigned* hrow = hc + (j << 8);
  float fg = 0.f;

  #pragma unroll 4
  for (int r = 0; r < 128; ++r) {
    float4 s = st[pixbase + r];
    unsigned meta = __float_as_uint(s.w);
    int id = (int)(meta & 0xFFu);
    float dx = s.x - cx, dy = s.y - cy;
    float dist = fast_exp(-(dx*dx*s0 + dy*dy*s1));
    bool own = (id == j+1);
    if (own) { float d = s.z - dist; fg += d*d; }
    if (meta & 0x100u) {
      float f = own ? (1.0f - dist) : dist;          // err/2
      unsigned bin = min((unsigned)(f * (2.0f*INV_BIN)), KB2-1u);
      atomicAdd(&hrow[bin], own ? 0x10001u : 1u);
    }
  }

  for (int o = 32; o; o >>= 1) fg += __shfl_down(fg, o);
  if (lane == 0) atomicAdd(&seedfg[b], 10.0f * fg);  // fg_w = 10

  __syncthreads();
  {
    uint4* dst = (uint4*)(hist + ((size_t)b*NCHUNK + chunk)*(NINST*KB2));
    const uint4* src = (const uint4*)hc;
    #pragma unroll
    for (int i = 0; i < NINST*KB2/4/K3T; ++i) dst[i*K3T + t] = src[i*K3T + t];
  }
}

// K4: per pair: 1024 threads; 4 groups each reduce 32 chunk-histograms,
// combine in LDS, then one wave does the descending Lovasz scan.
__global__ __launch_bounds__(1024) void k4_scan(
    const unsigned* __restrict__ hist, const float* __restrict__ der,
    float* __restrict__ instl)
{
  __shared__ unsigned s_c[4][KB2], s_p[4][KB2];
  int t = threadIdx.x;
  int pair = blockIdx.x;
  int b = pair >> 5, j = pair & 31;
  int bin = t & (KB2-1), grp = t >> 8;
  const unsigned* basep = hist + ((size_t)b*NCHUNK*NINST + j)*KB2 + bin;
  unsigned c = 0, p = 0;
  #pragma unroll 8
  for (int ch = grp*(NCHUNK/4); ch < (grp+1)*(NCHUNK/4); ++ch) {
    unsigned v = basep[(size_t)ch * (NINST*KB2)];
    c += v & 0xFFFFu; p += v >> 16;
  }
  s_c[grp][bin] = c; s_p[grp][bin] = p;
  __syncthreads();
  if (t < KB2) {
    s_c[0][t] = s_c[0][t] + s_c[1][t] + s_c[2][t] + s_c[3][t];
    s_p[0][t] = s_p[0][t] + s_p[1][t] + s_p[2][t] + s_p[3][t];
  }
  __syncthreads();

  if (t < 64) {
    int lane = t;
    float G = der[5*128+pair];
    unsigned carryN = 0, carryP = 0;
    float Jprev = 0.f, L = 0.f;
    for (int c8 = 0; c8 < KB2/64; ++c8) {
      int k = KB2 - 1 - c8*64 - lane;
      unsigned n = s_c[0][k], pp0 = s_p[0][k];
      for (int off = 1; off < 64; off <<= 1) {
        unsigned nn = __shfl_up(n, off);
        unsigned pp = __shfl_up(pp0, off);
        if (lane >= off) { n += nn; pp0 += pp; }
      }
      float fN = (float)(carryN + n);
      float fP = (float)(carryP + pp0);
      float uni = G + fN - fP;
      float J = 1.0f - (G - fP) / fmaxf(uni, 1e-9f);
      float Jp = __shfl_up(J, 1);
      if (lane == 0) Jp = Jprev;
      float v = (k + 0.5f) * (1.0f/INV_BIN);
      L += v * (J - Jp);
      carryN += __shfl(n, 63);
      carryP += __shfl(pp0, 63);
      Jprev  = __shfl(J, 63);
    }
    for (int o = 32; o; o >>= 1) L += __shfl_down(L, o);
    if (lane == 0) instl[pair] = L;
  }
}

// K5: final combine.
__global__ void k5_final(const float* __restrict__ instl, const float* __restrict__ der,
                         const float* __restrict__ seedbg, const float* __restrict__ seedfg,
                         float* __restrict__ out)
{
  __shared__ float red[128];
  int t = threadIdx.x;
  float v = instl[t]*(1.0f/NINST) + 10.0f*der[4*128+t]*(1.0f/NINST);
  red[t] = v; __syncthreads();
  for (int s = 64; s; s >>= 1) { if (t < s) red[t] += red[t+s]; __syncthreads(); }
  if (t == 0) {
    float tot = red[0];
    for (int b = 0; b < BB; ++b) tot += (seedbg[b] + seedfg[b]) * (1.0f/NPIX);
    out[0] = tot * (1.0f/BB);
  }
}

extern "C" void kernel_launch(void* const* d_in, const int* in_sizes, int n_in,
                              void* d_out, int out_size, void* d_ws, size_t ws_size,
                              hipStream_t stream)
{
  const float* pred = (const float*)d_in[0];
  const int* inst = (const int*)d_in[1];
  const int* lab  = (const int*)d_in[2];
  char* ws = (char*)d_ws;
  float* stats = (float*)(ws + OFF_STATS);
  int* clsg = (int*)(ws + OFF_CLS);
  float* seedbg = (float*)(ws + OFF_SEED);
  float* seedfg = seedbg + 4;
  float* der = (float*)(ws + OFF_DER);
  float* instl = (float*)(ws + OFF_INSTL);
  unsigned short* sgown = (unsigned short*)(ws + OFF_SGOWN);
  unsigned* hist = (unsigned*)(ws + OFF_HIST);

  hipMemsetAsync(ws, 0, ZERO_BYTES, stream);
  hipLaunchKernelGGL(k1_stats, dim3(BB*256), dim3(256), 0, stream,
                     pred, inst, lab, stats, clsg, seedbg, sgown);
  hipLaunchKernelGGL(k2_derive, dim3(1), dim3(128), 0, stream, stats, clsg, der);
  hipLaunchKernelGGL(k3_hist, dim3(BB*NCHUNK), dim3(K3T), 0, stream,
                     pred, inst, lab, sgown, der, hist, seedfg);
  hipLaunchKernelGGL(k4_scan, dim3(128), dim3(1024), 0, stream, hist, der, instl);
  hipLaunchKernelGGL(k5_final, dim3(1), dim3(128), 0, stream, instl, der, seedbg, seedfg, (float*)d_out);
}